// Round 1
// baseline (1011.786 us; speedup 1.0000x reference)
//
#include <hip/hip_runtime.h>
#include <hip/hip_bf16.h>

typedef __attribute__((ext_vector_type(8))) short bf16x8; // 8 bf16 in 4 VGPRs
typedef __attribute__((ext_vector_type(4))) float f32x4;

#define MFMA16(a, b, c) __builtin_amdgcn_mfma_f32_16x16x32_bf16(a, b, c, 0, 0, 0)

static constexpr int S  = 4096;
static constexpr int Dm = 512;
static constexpr int Hh = 256;
static constexpr int Bb = 4;

// ---------------------------------------------------------------------------
// Projection GEMM: out = bf16((X @ W + bias) * scale); X:[M,512] fp32, W:[512,N] fp32.
// transpose_out=1 stores out[b][n][s] (v^T layout) instead of out[m][n].
// Tile: 64x64 per 256-thread block; wave w owns rows 16w..16w+15, all 64 cols.
// ---------------------------------------------------------------------------
__global__ __launch_bounds__(256) void proj_kernel(
    const float* __restrict__ X,
    const float* __restrict__ W,
    const float* __restrict__ bias,
    __hip_bfloat16* __restrict__ out,
    int N, float scale, int transpose_out)
{
    __shared__ __hip_bfloat16 a_lds[64][32];  // [m][k]
    __shared__ __hip_bfloat16 w_lds[64][32];  // [n][k] (W^T)

    const int tid  = threadIdx.x;
    const int lane = tid & 63;
    const int wave = tid >> 6;
    const int lr   = lane & 15;
    const int lg   = lane >> 4;
    const int m0   = blockIdx.y * 64;
    const int n0   = blockIdx.x * 64;

    f32x4 acc[4];
    #pragma unroll
    for (int n = 0; n < 4; ++n) acc[n] = (f32x4){0.f, 0.f, 0.f, 0.f};

    for (int k0 = 0; k0 < 512; k0 += 32) {
        __syncthreads();
        {   // stage A (x) tile, cast fp32->bf16. 64 rows x 32 k.
            int row = tid >> 2, off = (tid & 3) * 8;
            const float* src = X + (size_t)(m0 + row) * 512 + k0 + off;
            #pragma unroll
            for (int j = 0; j < 8; ++j) a_lds[row][off + j] = __float2bfloat16(src[j]);
        }
        {   // stage W^T tile. W rows k0..k0+31, cols n0..n0+63.
            int kk = tid >> 3, noff = (tid & 7) * 8;
            const float* src = W + (size_t)(k0 + kk) * N + n0 + noff;
            #pragma unroll
            for (int j = 0; j < 8; ++j) w_lds[noff + j][kk] = __float2bfloat16(src[j]);
        }
        __syncthreads();
        bf16x8 af = *(const bf16x8*)&a_lds[wave * 16 + lr][lg * 8];
        #pragma unroll
        for (int n = 0; n < 4; ++n) {
            bf16x8 bfr = *(const bf16x8*)&w_lds[n * 16 + lr][lg * 8];
            acc[n] = MFMA16(af, bfr, acc[n]);
        }
    }

    #pragma unroll
    for (int n = 0; n < 4; ++n) {
        int col = n0 + n * 16 + lr;
        float bia = bias[col];
        #pragma unroll
        for (int r = 0; r < 4; ++r) {
            int row = m0 + wave * 16 + lg * 4 + r;  // global m (= b*4096 + s)
            float val = (acc[n][r] + bia) * scale;
            if (!transpose_out) {
                out[(size_t)row * N + col] = __float2bfloat16(val);
            } else {
                int bidx = row >> 12, s = row & 4095;
                out[((size_t)bidx * N + col) * S + s] = __float2bfloat16(val);
            }
        }
    }
}

// ---------------------------------------------------------------------------
// Attention: one block (4 waves) per (batch, 64 q-rows). Wave w owns q-rows
// 16w..16w+15. Pass 1: exact softmax stats (online max/sum over k-tiles).
// Pass 2: recompute scores, p = exp(s-m)/l, attn = fmf(p) -> fp32 out;
// P->bf16 via LDS relayout -> PV MFMA accumulate (full D=512 per wave).
// ---------------------------------------------------------------------------
__global__ __launch_bounds__(256) void attn_kernel(
    const __hip_bfloat16* __restrict__ Q,   // [B][S][H], 1/sqrt(H) pre-applied
    const __hip_bfloat16* __restrict__ K,   // [B][S][H]
    const __hip_bfloat16* __restrict__ VT,  // [B][D][S]
    float* __restrict__ out,                // [B][S][D]
    float* __restrict__ attn)               // [B][S][S]
{
    __shared__ __hip_bfloat16 k_lds[64][256];   // 32 KB
    __shared__ __hip_bfloat16 vt_lds[512][64];  // 64 KB
    __shared__ __hip_bfloat16 p_lds[64][64];    // 8 KB

    const int tid  = threadIdx.x;
    const int lane = tid & 63;
    const int wave = tid >> 6;
    const int lr   = lane & 15;
    const int lg   = lane >> 4;
    const int b    = blockIdx.y;
    const int q0   = blockIdx.x * 64;

    const __hip_bfloat16* Qb  = Q  + ((size_t)b * S + q0) * Hh;
    const __hip_bfloat16* Kb  = K  + (size_t)b * S * Hh;
    const __hip_bfloat16* VTb = VT + (size_t)b * Dm * S;

    // Hoist Q fragments for this wave's 16 rows (8 k-steps of 32 over H=256).
    bf16x8 qf[8];
    #pragma unroll
    for (int h = 0; h < 8; ++h)
        qf[h] = *(const bf16x8*)&Qb[(size_t)(wave * 16 + lr) * Hh + h * 32 + lg * 8];

    float m_run[4], l_run[4];
    #pragma unroll
    for (int r = 0; r < 4; ++r) { m_run[r] = -1e30f; l_run[r] = 0.f; }

    // ---------------- pass 1: softmax stats ----------------
    for (int kt = 0; kt < 64; ++kt) {
        __syncthreads();
        for (int i = tid; i < 64 * 32; i += 256) {
            int r = i >> 5, c = (i & 31) * 8;
            *(uint4*)&k_lds[r][c] = *(const uint4*)&Kb[(size_t)(kt * 64 + r) * Hh + c];
        }
        __syncthreads();

        f32x4 acc[4];
        #pragma unroll
        for (int n = 0; n < 4; ++n) acc[n] = (f32x4){0.f, 0.f, 0.f, 0.f};
        #pragma unroll
        for (int n = 0; n < 4; ++n)
            #pragma unroll
            for (int h = 0; h < 8; ++h) {
                bf16x8 kf = *(const bf16x8*)&k_lds[n * 16 + lr][h * 32 + lg * 8];
                acc[n] = MFMA16(qf[h], kf, acc[n]);
            }

        #pragma unroll
        for (int r = 0; r < 4; ++r) {
            float mx = fmaxf(fmaxf(acc[0][r], acc[1][r]), fmaxf(acc[2][r], acc[3][r]));
            #pragma unroll
            for (int m = 1; m < 16; m <<= 1) mx = fmaxf(mx, __shfl_xor(mx, m));
            float mnew = fmaxf(m_run[r], mx);
            float ssum = __expf(acc[0][r] - mnew) + __expf(acc[1][r] - mnew)
                       + __expf(acc[2][r] - mnew) + __expf(acc[3][r] - mnew);
            #pragma unroll
            for (int m = 1; m < 16; m <<= 1) ssum += __shfl_xor(ssum, m);
            l_run[r] = l_run[r] * __expf(m_run[r] - mnew) + ssum;
            m_run[r] = mnew;
        }
    }

    float inv_l[4];
    #pragma unroll
    for (int r = 0; r < 4; ++r) inv_l[r] = 1.0f / l_run[r];

    f32x4 oacc[32];
    #pragma unroll
    for (int n = 0; n < 32; ++n) oacc[n] = (f32x4){0.f, 0.f, 0.f, 0.f};

    // ---------------- pass 2: attn write + PV ----------------
    for (int kt = 0; kt < 64; ++kt) {
        __syncthreads();
        for (int i = tid; i < 64 * 32; i += 256) {
            int r = i >> 5, c = (i & 31) * 8;
            *(uint4*)&k_lds[r][c] = *(const uint4*)&Kb[(size_t)(kt * 64 + r) * Hh + c];
        }
        for (int i = tid; i < 512 * 8; i += 256) {
            int r = i >> 3, c = (i & 7) * 8;
            *(uint4*)&vt_lds[r][c] = *(const uint4*)&VTb[(size_t)r * S + kt * 64 + c];
        }
        __syncthreads();

        f32x4 acc[4];
        #pragma unroll
        for (int n = 0; n < 4; ++n) acc[n] = (f32x4){0.f, 0.f, 0.f, 0.f};
        #pragma unroll
        for (int n = 0; n < 4; ++n)
            #pragma unroll
            for (int h = 0; h < 8; ++h) {
                bf16x8 kf = *(const bf16x8*)&k_lds[n * 16 + lr][h * 32 + lg * 8];
                acc[n] = MFMA16(qf[h], kf, acc[n]);
            }

        // softmax + fuzzy clamp; write attn (fp32) and P (bf16) for PV.
        #pragma unroll
        for (int n = 0; n < 4; ++n)
            #pragma unroll
            for (int r = 0; r < 4; ++r) {
                float p = __expf(acc[n][r] - m_run[r]) * inv_l[r];
                float f = fmaxf(fminf(p, 1.0f - p) * (1.0f / 0.3f), 0.0f);
                int row = wave * 16 + lg * 4 + r;
                int col = n * 16 + lr;
                attn[((size_t)(b * S + q0 + row)) * S + kt * 64 + col] = f;
                p_lds[row][col] = __float2bfloat16(f);
            }
        __syncthreads();  // p_lds visible (wave-local in fact, but be safe)

        bf16x8 pf0 = *(const bf16x8*)&p_lds[wave * 16 + lr][lg * 8];
        bf16x8 pf1 = *(const bf16x8*)&p_lds[wave * 16 + lr][32 + lg * 8];
        #pragma unroll
        for (int n2 = 0; n2 < 32; ++n2) {
            bf16x8 vf0 = *(const bf16x8*)&vt_lds[n2 * 16 + lr][lg * 8];
            bf16x8 vf1 = *(const bf16x8*)&vt_lds[n2 * 16 + lr][32 + lg * 8];
            oacc[n2] = MFMA16(pf0, vf0, oacc[n2]);
            oacc[n2] = MFMA16(pf1, vf1, oacc[n2]);
        }
    }

    // epilogue: write out [B][S][D] fp32
    #pragma unroll
    for (int n2 = 0; n2 < 32; ++n2)
        #pragma unroll
        for (int r = 0; r < 4; ++r) {
            int row = q0 + wave * 16 + lg * 4 + r;
            out[((size_t)(b * S + row)) * Dm + n2 * 16 + lr] = oacc[n2][r];
        }
}

// ---------------------------------------------------------------------------
extern "C" void kernel_launch(void* const* d_in, const int* in_sizes, int n_in,
                              void* d_out, int out_size, void* d_ws, size_t ws_size,
                              hipStream_t stream) {
    const float* x  = (const float*)d_in[0];
    const float* Wq = (const float*)d_in[1];
    const float* bq = (const float*)d_in[2];
    const float* Wk = (const float*)d_in[3];
    const float* bk = (const float*)d_in[4];
    const float* Wv = (const float*)d_in[5];
    const float* bv = (const float*)d_in[6];

    float* out  = (float*)d_out;                      // [4,4096,512]
    float* attn = out + (size_t)Bb * S * Dm;          // [4,4096,4096]

    __hip_bfloat16* q_ws  = (__hip_bfloat16*)d_ws;              // [B][S][H]  8 MB
    __hip_bfloat16* k_ws  = q_ws + (size_t)Bb * S * Hh;         // [B][S][H]  8 MB
    __hip_bfloat16* vt_ws = k_ws + (size_t)Bb * S * Hh;         // [B][D][S] 16 MB

    const float scale = 0.0625f;  // 1/sqrt(256)

    // q = (x@Wq + bq) * scale ; k = x@Wk + bk ; v^T = (x@Wv + bv)^T
    proj_kernel<<<dim3(Hh / 64, (Bb * S) / 64), 256, 0, stream>>>(x, Wq, bq, q_ws, Hh, scale, 0);
    proj_kernel<<<dim3(Hh / 64, (Bb * S) / 64), 256, 0, stream>>>(x, Wk, bk, k_ws, Hh, 1.0f, 0);
    proj_kernel<<<dim3(Dm / 64, (Bb * S) / 64), 256, 0, stream>>>(x, Wv, bv, vt_ws, Dm, 1.0f, 1);

    attn_kernel<<<dim3(S / 64, Bb), 256, 0, stream>>>(q_ws, k_ws, vt_ws, out, attn);
}

// Round 2
// 405.219 us; speedup vs baseline: 2.4969x; 2.4969x over previous
//
#include <hip/hip_runtime.h>
#include <hip/hip_bf16.h>

typedef __attribute__((ext_vector_type(8))) short bf16x8; // 8 bf16 in 4 VGPRs
typedef __attribute__((ext_vector_type(4))) float f32x4;

#define MFMA16(a, b, c) __builtin_amdgcn_mfma_f32_16x16x32_bf16(a, b, c, 0, 0, 0)

static constexpr int S  = 4096;
static constexpr int Dm = 512;
static constexpr int Hh = 256;
static constexpr int Bb = 4;

// Swizzled LDS index helpers (bf16 units; 16B slot = 8 bf16 granularity).
// XOR low 3 slot bits with (row&7): spreads the "16 lanes read 16 rows at the
// same column" MFMA-fragment pattern across all 32 banks (G4 fix).
__device__ __forceinline__ int kidx(int r, int c) { return r * 256 + (c ^ ((r & 7) << 3)); }
__device__ __forceinline__ int vidx(int r, int c) { return r * 64  + (c ^ ((r & 7) << 3)); }
__device__ __forceinline__ int pidx(int r, int c) { return r * 64  + (c ^ ((r & 7) << 3)); }

// ---------------------------------------------------------------------------
// Projection GEMM (unchanged, known-good): out = bf16((X@W + bias)*scale).
// ---------------------------------------------------------------------------
__global__ __launch_bounds__(256) void proj_kernel(
    const float* __restrict__ X,
    const float* __restrict__ W,
    const float* __restrict__ bias,
    __hip_bfloat16* __restrict__ out,
    int N, float scale, int transpose_out)
{
    __shared__ __hip_bfloat16 a_lds[64][32];
    __shared__ __hip_bfloat16 w_lds[64][32];

    const int tid  = threadIdx.x;
    const int lane = tid & 63;
    const int wave = tid >> 6;
    const int lr   = lane & 15;
    const int lg   = lane >> 4;
    const int m0   = blockIdx.y * 64;
    const int n0   = blockIdx.x * 64;

    f32x4 acc[4];
    #pragma unroll
    for (int n = 0; n < 4; ++n) acc[n] = (f32x4){0.f, 0.f, 0.f, 0.f};

    for (int k0 = 0; k0 < 512; k0 += 32) {
        __syncthreads();
        {
            int row = tid >> 2, off = (tid & 3) * 8;
            const float* src = X + (size_t)(m0 + row) * 512 + k0 + off;
            #pragma unroll
            for (int j = 0; j < 8; ++j) a_lds[row][off + j] = __float2bfloat16(src[j]);
        }
        {
            int kk = tid >> 3, noff = (tid & 7) * 8;
            const float* src = W + (size_t)(k0 + kk) * N + n0 + noff;
            #pragma unroll
            for (int j = 0; j < 8; ++j) w_lds[noff + j][kk] = __float2bfloat16(src[j]);
        }
        __syncthreads();
        bf16x8 af = *(const bf16x8*)&a_lds[wave * 16 + lr][lg * 8];
        #pragma unroll
        for (int n = 0; n < 4; ++n) {
            bf16x8 bfr = *(const bf16x8*)&w_lds[n * 16 + lr][lg * 8];
            acc[n] = MFMA16(af, bfr, acc[n]);
        }
    }

    #pragma unroll
    for (int n = 0; n < 4; ++n) {
        int col = n0 + n * 16 + lr;
        float bia = bias[col];
        #pragma unroll
        for (int r = 0; r < 4; ++r) {
            int row = m0 + wave * 16 + lg * 4 + r;
            float val = (acc[n][r] + bia) * scale;
            if (!transpose_out) {
                out[(size_t)row * N + col] = __float2bfloat16(val);
            } else {
                int bidx = row >> 12, s = row & 4095;
                out[((size_t)bidx * N + col) * S + s] = __float2bfloat16(val);
            }
        }
    }
}

// ---------------------------------------------------------------------------
// Attention v2: 512 threads (8 waves) per (batch, 64 q-rows).
// Wave w: qg = w>>1 owns q-rows [16*qg,16*qg+16); half = w&1 owns kv-cols
// [32*half, 32*half+32) of each kv-tile for QK^T.
// Pass 1: partial softmax stats per (qg,half), merged via LDS at the end.
// Pass 2: QK^T (split as pass 1) -> softmax+fmf -> attn write + p_lds;
//         PV d-split: wave w owns d-slice [64*w, 64*w+64) -> VT LDS bytes
//         are read exactly once. All LDS tiles XOR-swizzled.
// ---------------------------------------------------------------------------
__global__ __launch_bounds__(512) void attn_kernel(
    const __hip_bfloat16* __restrict__ Q,   // [B][S][H], 1/sqrt(H) pre-applied
    const __hip_bfloat16* __restrict__ K,   // [B][S][H]
    const __hip_bfloat16* __restrict__ VT,  // [B][D][S]
    float* __restrict__ out,                // [B][S][D]
    float* __restrict__ attn)               // [B][S][S]
{
    __shared__ __hip_bfloat16 k_lds[64 * 256];   // 32 KB (swizzled)
    __shared__ __hip_bfloat16 vt_lds[512 * 64];  // 64 KB (swizzled)
    __shared__ __hip_bfloat16 p_lds[64 * 64];    // 8 KB  (swizzled)
    __shared__ float stats_lds[2][4][16][2];     // 1 KB

    const int tid  = threadIdx.x;
    const int lane = tid & 63;
    const int w    = tid >> 6;   // 0..7
    const int lr   = lane & 15;
    const int lg   = lane >> 4;
    const int qg   = w >> 1;     // 0..3
    const int half = w & 1;      // 0..1
    const int b    = blockIdx.y;
    const int q0   = blockIdx.x * 64;

    const __hip_bfloat16* Qb  = Q  + ((size_t)b * S + q0) * Hh;
    const __hip_bfloat16* Kb  = K  + (size_t)b * S * Hh;
    const __hip_bfloat16* VTb = VT + (size_t)b * Dm * S;

    // Q fragments for this wave's 16 q-rows (8 k-steps over H=256).
    bf16x8 qf[8];
    #pragma unroll
    for (int h = 0; h < 8; ++h)
        qf[h] = *(const bf16x8*)&Qb[(size_t)(qg * 16 + lr) * Hh + h * 32 + lg * 8];

    float m_p[4], l_p[4];
    #pragma unroll
    for (int r = 0; r < 4; ++r) { m_p[r] = -1e30f; l_p[r] = 0.f; }

    // ---------------- pass 1: partial softmax stats ----------------
    for (int kt = 0; kt < 64; ++kt) {
        __syncthreads();
        {   // stage K tile (swizzled): thread -> row=tid>>3, 4x 16B chunks
            int row = tid >> 3, cb = (tid & 7) * 8;
            const __hip_bfloat16* src = Kb + (size_t)(kt * 64 + row) * Hh + cb;
            #pragma unroll
            for (int c0 = 0; c0 < 4; ++c0)
                *(uint4*)&k_lds[kidx(row, cb + c0 * 64)] = *(const uint4*)&src[c0 * 64];
        }
        __syncthreads();

        f32x4 acc[2];
        #pragma unroll
        for (int nn = 0; nn < 2; ++nn) acc[nn] = (f32x4){0.f, 0.f, 0.f, 0.f};
        #pragma unroll
        for (int nn = 0; nn < 2; ++nn) {
            int n = half * 2 + nn;
            #pragma unroll
            for (int h = 0; h < 8; ++h) {
                bf16x8 kf = *(const bf16x8*)&k_lds[kidx(n * 16 + lr, h * 32 + lg * 8)];
                acc[nn] = MFMA16(qf[h], kf, acc[nn]);
            }
        }
        #pragma unroll
        for (int r = 0; r < 4; ++r) {
            float mx = fmaxf(acc[0][r], acc[1][r]);
            #pragma unroll
            for (int m = 1; m < 16; m <<= 1) mx = fmaxf(mx, __shfl_xor(mx, m));
            float mnew = fmaxf(m_p[r], mx);
            float ssum = __expf(acc[0][r] - mnew) + __expf(acc[1][r] - mnew);
            #pragma unroll
            for (int m = 1; m < 16; m <<= 1) ssum += __shfl_xor(ssum, m);
            l_p[r] = l_p[r] * __expf(m_p[r] - mnew) + ssum;
            m_p[r] = mnew;
        }
    }

    // merge the two kv-halves' partial stats (associative (m,l) merge)
    if (lr == 0) {
        #pragma unroll
        for (int r = 0; r < 4; ++r) {
            stats_lds[half][qg][lg * 4 + r][0] = m_p[r];
            stats_lds[half][qg][lg * 4 + r][1] = l_p[r];
        }
    }
    __syncthreads();
    float m_f[4], inv_l[4];
    #pragma unroll
    for (int r = 0; r < 4; ++r) {
        float mo = stats_lds[half ^ 1][qg][lg * 4 + r][0];
        float lo = stats_lds[half ^ 1][qg][lg * 4 + r][1];
        float mm = fmaxf(m_p[r], mo);
        float ll = l_p[r] * __expf(m_p[r] - mm) + lo * __expf(mo - mm);
        m_f[r]   = mm;
        inv_l[r] = 1.0f / ll;
    }

    f32x4 oacc[4][4];
    #pragma unroll
    for (int qt = 0; qt < 4; ++qt)
        #pragma unroll
        for (int dt = 0; dt < 4; ++dt) oacc[qt][dt] = (f32x4){0.f, 0.f, 0.f, 0.f};

    // ---------------- pass 2: attn write + PV ----------------
    for (int kt = 0; kt < 64; ++kt) {
        __syncthreads();
        {   // stage K tile
            int row = tid >> 3, cb = (tid & 7) * 8;
            const __hip_bfloat16* src = Kb + (size_t)(kt * 64 + row) * Hh + cb;
            #pragma unroll
            for (int c0 = 0; c0 < 4; ++c0)
                *(uint4*)&k_lds[kidx(row, cb + c0 * 64)] = *(const uint4*)&src[c0 * 64];
        }
        {   // stage VT tile: 8 iters, lanes 0..7 cover one 128B row-chunk
            int rb = tid >> 3, cb = (tid & 7) * 8;
            #pragma unroll
            for (int j = 0; j < 8; ++j) {
                int row = j * 64 + rb;
                *(uint4*)&vt_lds[vidx(row, cb)] =
                    *(const uint4*)&VTb[(size_t)row * S + kt * 64 + cb];
            }
        }
        __syncthreads();

        f32x4 acc[2];
        #pragma unroll
        for (int nn = 0; nn < 2; ++nn) acc[nn] = (f32x4){0.f, 0.f, 0.f, 0.f};
        #pragma unroll
        for (int nn = 0; nn < 2; ++nn) {
            int n = half * 2 + nn;
            #pragma unroll
            for (int h = 0; h < 8; ++h) {
                bf16x8 kf = *(const bf16x8*)&k_lds[kidx(n * 16 + lr, h * 32 + lg * 8)];
                acc[nn] = MFMA16(qf[h], kf, acc[nn]);
            }
        }

        // softmax + fuzzy clamp; write attn (fp32) + P (bf16, swizzled)
        #pragma unroll
        for (int nn = 0; nn < 2; ++nn)
            #pragma unroll
            for (int r = 0; r < 4; ++r) {
                float p = __expf(acc[nn][r] - m_f[r]) * inv_l[r];
                float f = fmaxf(fminf(p, 1.0f - p) * (1.0f / 0.3f), 0.0f);
                int row_l = qg * 16 + lg * 4 + r;
                int col_l = (half * 2 + nn) * 16 + lr;
                attn[((size_t)(b * S + q0 + row_l)) * S + kt * 64 + col_l] = f;
                p_lds[pidx(row_l, col_l)] = __float2bfloat16(f);
            }
        __syncthreads();  // p_lds complete before cross-wave PV reads

        // PV: wave w owns d-slice [64w, 64w+64)
        bf16x8 pf[4][2];
        #pragma unroll
        for (int qt = 0; qt < 4; ++qt)
            #pragma unroll
            for (int ks = 0; ks < 2; ++ks)
                pf[qt][ks] = *(const bf16x8*)&p_lds[pidx(qt * 16 + lr, ks * 32 + lg * 8)];
        #pragma unroll
        for (int dt = 0; dt < 4; ++dt)
            #pragma unroll
            for (int ks = 0; ks < 2; ++ks) {
                bf16x8 vf = *(const bf16x8*)&vt_lds[vidx(w * 64 + dt * 16 + lr, ks * 32 + lg * 8)];
                #pragma unroll
                for (int qt = 0; qt < 4; ++qt)
                    oacc[qt][dt] = MFMA16(pf[qt][ks], vf, oacc[qt][dt]);
            }
    }

    // epilogue: out[B][S][D] fp32; wave w writes its d-slice
    #pragma unroll
    for (int qt = 0; qt < 4; ++qt)
        #pragma unroll
        for (int dt = 0; dt < 4; ++dt)
            #pragma unroll
            for (int r = 0; r < 4; ++r) {
                int row = q0 + qt * 16 + lg * 4 + r;
                out[((size_t)(b * S + row)) * Dm + w * 64 + dt * 16 + lr] = oacc[qt][dt][r];
            }
}

// ---------------------------------------------------------------------------
extern "C" void kernel_launch(void* const* d_in, const int* in_sizes, int n_in,
                              void* d_out, int out_size, void* d_ws, size_t ws_size,
                              hipStream_t stream) {
    const float* x  = (const float*)d_in[0];
    const float* Wq = (const float*)d_in[1];
    const float* bq = (const float*)d_in[2];
    const float* Wk = (const float*)d_in[3];
    const float* bk = (const float*)d_in[4];
    const float* Wv = (const float*)d_in[5];
    const float* bv = (const float*)d_in[6];

    float* out  = (float*)d_out;                      // [4,4096,512]
    float* attn = out + (size_t)Bb * S * Dm;          // [4,4096,4096]

    __hip_bfloat16* q_ws  = (__hip_bfloat16*)d_ws;              // [B][S][H]
    __hip_bfloat16* k_ws  = q_ws + (size_t)Bb * S * Hh;         // [B][S][H]
    __hip_bfloat16* vt_ws = k_ws + (size_t)Bb * S * Hh;         // [B][D][S]

    const float scale = 0.0625f;  // 1/sqrt(256)

    proj_kernel<<<dim3(Hh / 64, (Bb * S) / 64), 256, 0, stream>>>(x, Wq, bq, q_ws, Hh, scale, 0);
    proj_kernel<<<dim3(Hh / 64, (Bb * S) / 64), 256, 0, stream>>>(x, Wk, bk, k_ws, Hh, 1.0f, 0);
    proj_kernel<<<dim3(Dm / 64, (Bb * S) / 64), 256, 0, stream>>>(x, Wv, bv, vt_ws, Dm, 1.0f, 1);

    attn_kernel<<<dim3(S / 64, Bb), 512, 0, stream>>>(q_ws, k_ws, vt_ws, out, attn);
}